// Round 1
// baseline (331.292 us; speedup 1.0000x reference)
//
#include <hip/hip_runtime.h>
#include <math.h>

#define NUM_CLASSES 124
#define FEAT_CH     64
#define OUT_HW      480
#define IN_HW       120
#define NPIX        (OUT_HW * OUT_HW)
#define EPSV        1e-8f

// LDS/partial layout: per class, 65 floats (64 channel acc + wsum), stride 65
// => bank(c,k) = (65c+k)%32 = (c+k)%32 -> full 32-bank spread for random c.
#define STRIDE_ACC   65
#define ACC_FLOATS   (NUM_CLASSES * STRIDE_ACC)        // 8060
#define SLICE_FLOATS (ACC_FLOATS + NUM_CLASSES)        // 8184 (+124 counts)

// ---------------- phase 0: mn = memory rows L2-normalized -> ws ----------------
__global__ void k_norm_mem(const float* __restrict__ mem, float* __restrict__ mn) {
    int c = blockIdx.x, k = threadIdx.x;     // 124 blocks x 64 threads (1 wave)
    float v = mem[c * FEAT_CH + k];
    float s = v * v;
#pragma unroll
    for (int off = 32; off; off >>= 1) s += __shfl_xor(s, off);
    float n = fmaxf(sqrtf(s), EPSV);
    mn[c * FEAT_CH + k] = v / n;
}

// ---------------- phase 1: per-pixel scatter-reduce into per-block LDS ---------
__global__ __launch_bounds__(256) void k_accum(
        const float* __restrict__ feats, const int* __restrict__ seg,
        const float* __restrict__ mn, float* __restrict__ part, int nb) {
    __shared__ float accL[ACC_FLOATS];
    __shared__ float mnL[ACC_FLOATS];       // stride 65, slot 64 unused
    __shared__ float cntL[NUM_CLASSES];

    const int tid = threadIdx.x;
    for (int i = tid; i < ACC_FLOATS; i += 256) accL[i] = 0.0f;
    for (int i = tid; i < NUM_CLASSES * FEAT_CH; i += 256)
        mnL[(i >> 6) * STRIDE_ACC + (i & 63)] = mn[i];
    for (int i = tid; i < NUM_CLASSES; i += 256) cntL[i] = 0.0f;
    __syncthreads();

    const int gsz = nb * 256;
    for (int p = blockIdx.x * 256 + tid; p < NPIX; p += gsz) {
        const int oy = p / OUT_HW;
        const int ox = p - oy * OUT_HW;
        // jax.image.resize bilinear, half-pixel centers; boundary renorm == clamp
        float fy = fminf(fmaxf(oy * 0.25f - 0.375f, 0.0f), (float)(IN_HW - 1));
        float fx = fminf(fmaxf(ox * 0.25f - 0.375f, 0.0f), (float)(IN_HW - 1));
        const int y0 = (int)fy, x0 = (int)fx;
        const float ty = fy - (float)y0, tx = fx - (float)x0;
        const int y1 = min(y0 + 1, IN_HW - 1), x1 = min(x0 + 1, IN_HW - 1);
        const int o00 = y0 * IN_HW + x0, o01 = y0 * IN_HW + x1;
        const int o10 = y1 * IN_HW + x0, o11 = y1 * IN_HW + x1;

        const int c = seg[p];
        const float* __restrict__ mrow = mnL + c * STRIDE_ACC;

        float xv[FEAT_CH];
        float nrm2 = 0.0f, dot = 0.0f;
#pragma unroll
        for (int k = 0; k < FEAT_CH; ++k) {
            const float* b = feats + k * (IN_HW * IN_HW);
            float a00 = b[o00], a01 = b[o01], a10 = b[o10], a11 = b[o11];
            float v0 = fmaf(tx, a01 - a00, a00);
            float v1 = fmaf(tx, a11 - a10, a10);
            float v  = fmaf(ty, v1 - v0, v0);
            xv[k] = v;
            nrm2 = fmaf(v, v, nrm2);
            dot  = fmaf(v, mrow[k], dot);
        }
        const float rn = 1.0f / fmaxf(sqrtf(nrm2), EPSV);
        const float w = 1.0f - dot * rn;   // for all-zero memory rows mn==0 -> w==1 (mean path)

        float* __restrict__ arow = accL + c * STRIDE_ACC;
#pragma unroll
        for (int k = 0; k < FEAT_CH; ++k) atomicAdd(&arow[k], w * xv[k]);
        atomicAdd(&arow[FEAT_CH], w);
        atomicAdd(&cntL[c], 1.0f);
    }
    __syncthreads();

    float* __restrict__ dst = part + (size_t)blockIdx.x * SLICE_FLOATS;
    for (int i = tid; i < ACC_FLOATS; i += 256) dst[i] = accL[i];
    for (int i = tid; i < NUM_CLASSES; i += 256) dst[ACC_FLOATS + i] = cntL[i];
}

// ---------------- phase 2: reduce partials + momentum/is_zero/present ----------
__global__ void k_final(const float* __restrict__ part, const float* __restrict__ mem,
                        float* __restrict__ out, int nb) {
    const int c = blockIdx.x, k = threadIdx.x;   // 124 blocks x 64 threads
    float acc = 0.0f, wsum = 0.0f, cnt = 0.0f;
    for (int b = 0; b < nb; ++b) {
        const float* __restrict__ sl = part + (size_t)b * SLICE_FLOATS;
        acc  += sl[c * STRIDE_ACC + k];
        wsum += sl[c * STRIDE_ACC + FEAT_CH];
        cnt  += sl[ACC_FLOATS + c];
    }
    const float m = mem[c * FEAT_CH + k];
    const int is_zero = __all(m == 0.0f);        // whole block is one wave
    // zero-mem classes accumulated with w==1, so wsum==count; divisor rule unifies:
    const float divisor = (wsum > 0.0f) ? wsum : 1.0f;
    const float val = acc / divisor;
    const float nw = is_zero ? val : fmaf(0.1f, val, 0.9f * m);
    out[c * FEAT_CH + k] = (cnt > 0.0f) ? nw : m;
}

extern "C" void kernel_launch(void* const* d_in, const int* in_sizes, int n_in,
                              void* d_out, int out_size, void* d_ws, size_t ws_size,
                              hipStream_t stream) {
    const float* feats  = (const float*)d_in[0];   // (1,64,120,120) f32
    const float* memory = (const float*)d_in[1];   // (124,1,64) f32
    const int*   seg    = (const int*)d_in[2];     // (1,480,480) i32
    float* out = (float*)d_out;                    // (124,1,64) f32
    float* ws  = (float*)d_ws;

    float* mn   = ws;                              // 7936 floats
    float* part = ws + NUM_CLASSES * FEAT_CH;

    // choose phase-1 grid from available workspace (constant across calls)
    long long avail = (long long)(ws_size / 4) - NUM_CLASSES * FEAT_CH;
    int nb = (int)(avail / SLICE_FLOATS);
    if (nb > 512) nb = 512;
    if (nb < 1)  nb = 1;

    k_norm_mem<<<NUM_CLASSES, FEAT_CH, 0, stream>>>(memory, mn);
    k_accum<<<nb, 256, 0, stream>>>(feats, seg, mn, part, nb);
    k_final<<<NUM_CLASSES, FEAT_CH, 0, stream>>>(part, memory, out, nb);
}

// Round 2
// 196.307 us; speedup vs baseline: 1.6876x; 1.6876x over previous
//
#include <hip/hip_runtime.h>
#include <math.h>

#define NUM_CLASSES 124
#define FEAT_CH     64
#define OUT_HW      480
#define IN_HW       120
#define NPIX        (OUT_HW * OUT_HW)
#define EPSV        1e-8f

// Accumulator layout: per class, 65 floats (64 channel acc + wsum), stride 65
// => bank(c,k) = (65c+k)%32 = (c+k)%32 -> full 32-bank spread for random c.
#define STRIDE_ACC   65
#define ACC_FLOATS   (NUM_CLASSES * STRIDE_ACC)        // 8060
#define ACC_TOTAL    (ACC_FLOATS + NUM_CLASSES)        // 8184 (+124 counts)
#define NB_ACCUM     512

// -------- phase 0 (fused): normalize memory rows -> mn, zero global acc --------
__global__ void k_prep(const float* __restrict__ mem, float* __restrict__ mn,
                       float* __restrict__ acc) {
    const int b = blockIdx.x;
    if (b < NUM_CLASSES) {
        if (threadIdx.x < FEAT_CH) {
            const int c = b, k = threadIdx.x;
            float v = mem[c * FEAT_CH + k];
            float s = v * v;
#pragma unroll
            for (int off = 32; off; off >>= 1) s += __shfl_xor(s, off);
            float n = fmaxf(sqrtf(s), EPSV);
            mn[c * FEAT_CH + k] = v / n;
        }
    } else {
        const int i = (b - NUM_CLASSES) * 256 + threadIdx.x;
        if (i < ACC_TOTAL) acc[i] = 0.0f;
    }
}

// ---------------- phase 1: per-pixel scatter-reduce into per-block LDS ---------
// then flush via global atomicAdd into the single 8184-float accumulator.
__global__ __launch_bounds__(256) void k_accum(
        const float* __restrict__ feats, const int* __restrict__ seg,
        const float* __restrict__ mn, float* __restrict__ acc) {
    __shared__ float accL[ACC_FLOATS];
    __shared__ float mnL[ACC_FLOATS];       // stride 65, slot 64 unused
    __shared__ float cntL[NUM_CLASSES];

    const int tid = threadIdx.x;
    for (int i = tid; i < ACC_FLOATS; i += 256) accL[i] = 0.0f;
    for (int i = tid; i < NUM_CLASSES * FEAT_CH; i += 256)
        mnL[(i >> 6) * STRIDE_ACC + (i & 63)] = mn[i];
    for (int i = tid; i < NUM_CLASSES; i += 256) cntL[i] = 0.0f;
    __syncthreads();

    const int gsz = NB_ACCUM * 256;
    for (int p = blockIdx.x * 256 + tid; p < NPIX; p += gsz) {
        const int oy = p / OUT_HW;
        const int ox = p - oy * OUT_HW;
        // jax.image.resize bilinear, half-pixel centers; boundary renorm == clamp
        float fy = fminf(fmaxf(oy * 0.25f - 0.375f, 0.0f), (float)(IN_HW - 1));
        float fx = fminf(fmaxf(ox * 0.25f - 0.375f, 0.0f), (float)(IN_HW - 1));
        const int y0 = (int)fy, x0 = (int)fx;
        const float ty = fy - (float)y0, tx = fx - (float)x0;
        const int y1 = min(y0 + 1, IN_HW - 1), x1 = min(x0 + 1, IN_HW - 1);
        const int o00 = y0 * IN_HW + x0, o01 = y0 * IN_HW + x1;
        const int o10 = y1 * IN_HW + x0, o11 = y1 * IN_HW + x1;

        const int c = seg[p];
        const float* __restrict__ mrow = mnL + c * STRIDE_ACC;

        float xv[FEAT_CH];
        float nrm2 = 0.0f, dot = 0.0f;
#pragma unroll
        for (int k = 0; k < FEAT_CH; ++k) {
            const float* b = feats + k * (IN_HW * IN_HW);
            float a00 = b[o00], a01 = b[o01], a10 = b[o10], a11 = b[o11];
            float v0 = fmaf(tx, a01 - a00, a00);
            float v1 = fmaf(tx, a11 - a10, a10);
            float v  = fmaf(ty, v1 - v0, v0);
            xv[k] = v;
            nrm2 = fmaf(v, v, nrm2);
            dot  = fmaf(v, mrow[k], dot);
        }
        const float rn = 1.0f / fmaxf(sqrtf(nrm2), EPSV);
        const float w = 1.0f - dot * rn;   // all-zero memory rows: mn==0 -> w==1 (mean path)

        float* __restrict__ arow = accL + c * STRIDE_ACC;
#pragma unroll
        for (int k = 0; k < FEAT_CH; ++k) atomicAdd(&arow[k], w * xv[k]);
        atomicAdd(&arow[FEAT_CH], w);
        atomicAdd(&cntL[c], 1.0f);
    }
    __syncthreads();

    // flush: skip zeros (adding 0 is identity; saves atomics for untouched slots)
    for (int i = tid; i < ACC_FLOATS; i += 256) {
        float v = accL[i];
        if (v != 0.0f) atomicAdd(&acc[i], v);
    }
    for (int i = tid; i < NUM_CLASSES; i += 256) {
        float v = cntL[i];
        if (v != 0.0f) atomicAdd(&acc[ACC_FLOATS + i], v);
    }
}

// ---------------- phase 2: momentum / is_zero / present selects ----------------
__global__ void k_final(const float* __restrict__ acc, const float* __restrict__ mem,
                        float* __restrict__ out) {
    const int c = blockIdx.x, k = threadIdx.x;   // 124 blocks x 64 threads (1 wave)
    const float a    = acc[c * STRIDE_ACC + k];
    const float wsum = acc[c * STRIDE_ACC + FEAT_CH];
    const float cnt  = acc[ACC_FLOATS + c];
    const float m = mem[c * FEAT_CH + k];
    const int is_zero = __all(m == 0.0f);        // whole block is one wave
    // zero-mem classes accumulated with w==1, so wsum==count; divisor rule unifies:
    const float divisor = (wsum > 0.0f) ? wsum : 1.0f;
    const float val = a / divisor;
    const float nw = is_zero ? val : fmaf(0.1f, val, 0.9f * m);
    out[c * FEAT_CH + k] = (cnt > 0.0f) ? nw : m;
}

extern "C" void kernel_launch(void* const* d_in, const int* in_sizes, int n_in,
                              void* d_out, int out_size, void* d_ws, size_t ws_size,
                              hipStream_t stream) {
    const float* feats  = (const float*)d_in[0];   // (1,64,120,120) f32
    const float* memory = (const float*)d_in[1];   // (124,1,64) f32
    const int*   seg    = (const int*)d_in[2];     // (1,480,480) i32
    float* out = (float*)d_out;                    // (124,1,64) f32
    float* ws  = (float*)d_ws;

    float* mn  = ws;                               // 7936 floats
    float* acc = ws + NUM_CLASSES * FEAT_CH;       // 8184 floats

    const int zero_blocks = (ACC_TOTAL + 255) / 256;          // 32
    k_prep<<<NUM_CLASSES + zero_blocks, 256, 0, stream>>>(memory, mn, acc);
    k_accum<<<NB_ACCUM, 256, 0, stream>>>(feats, seg, mn, acc);
    k_final<<<NUM_CLASSES, FEAT_CH, 0, stream>>>(acc, memory, out);
}

// Round 3
// 170.760 us; speedup vs baseline: 1.9401x; 1.1496x over previous
//
#include <hip/hip_runtime.h>
#include <math.h>

#define NUM_CLASSES 124
#define FEAT_CH     64
#define OUT_HW      480
#define IN_HW       120
#define NPIX        (OUT_HW * OUT_HW)
#define NCELL       (IN_HW * IN_HW)
#define NQUAD       (NPIX / 4)          // 57600: 120 quads/row x 480 rows
#define EPSV        1e-8f

// Accumulator layout: per class, 65 floats (64 ch + wsum), stride 65
// bank(c,k) = (c+k)%32 -> good spread for random classes.
#define STRIDE_ACC   65
#define ACC_FLOATS   (NUM_CLASSES * STRIDE_ACC)        // 8060
#define ACC_TOTAL    (ACC_FLOATS + NUM_CLASSES)        // 8184
#define NB_ACCUM     1024

// ws layout (floats): mn[7936] | acc[8184] | fT[14400*64]
#define WS_MN   0
#define WS_ACC  (NUM_CLASSES * FEAT_CH)
#define WS_FT   (WS_ACC + ACC_TOTAL)

// ---- phase 0 (fused): normalize memory, zero acc, transpose feats -> fT[q][k]
__global__ __launch_bounds__(256) void k_prep(
        const float* __restrict__ mem, const float* __restrict__ feats,
        float* __restrict__ mn, float* __restrict__ acc, float* __restrict__ fT) {
    const int b = blockIdx.x;
    if (b < NUM_CLASSES) {
        if (threadIdx.x < FEAT_CH) {
            const int c = b, k = threadIdx.x;
            float v = mem[c * FEAT_CH + k];
            float s = v * v;
#pragma unroll
            for (int off = 32; off; off >>= 1) s += __shfl_xor(s, off);
            mn[c * FEAT_CH + k] = v / fmaxf(sqrtf(s), EPSV);
        }
    } else if (b < NUM_CLASSES + 32) {
        const int i = (b - NUM_CLASSES) * 256 + threadIdx.x;
        if (i < ACC_TOTAL) acc[i] = 0.0f;
    } else {
        // transpose: one wave handles one cell q (64 channels)
        const int idx = (b - NUM_CLASSES - 32) * 256 + threadIdx.x;
        const int q = idx >> 6, k = idx & 63;
        fT[q * FEAT_CH + k] = feats[k * NCELL + q];
    }
}

// ---- phase 1: wave = 4 output pixels (quad) x 16 lanes, 4 channels per lane --
__global__ __launch_bounds__(256) void k_accum(
        const float* __restrict__ fT, const int* __restrict__ seg,
        const float* __restrict__ mn, float* __restrict__ acc) {
    __shared__ float accL[ACC_FLOATS];
    __shared__ float cntL[NUM_CLASSES];

    const int tid = threadIdx.x;
    for (int i = tid; i < ACC_FLOATS; i += 256) accL[i] = 0.0f;
    for (int i = tid; i < NUM_CLASSES; i += 256) cntL[i] = 0.0f;
    __syncthreads();

    const int lane = tid & 63;
    const int j = lane >> 4;          // pixel within quad (0..3)
    const int g = lane & 15;          // channel group (4 ch each)
    const int wid = (blockIdx.x * 256 + tid) >> 6;
    const int nwaves = NB_ACCUM * 4;
    const float4* __restrict__ fT4 = (const float4*)fT;
    const float4* __restrict__ mn4 = (const float4*)mn;

    for (int Q = wid; Q < NQUAD; Q += nwaves) {
        const int oy = Q / 120;
        const int a  = Q - oy * 120;          // input column anchor
        // y interp (uniform across quad)
        float fy = fminf(fmaxf(oy * 0.25f - 0.375f, 0.0f), (float)(IN_HW - 1));
        const int y0 = (int)fy; const float ty = fy - (float)y0;
        const int y1 = min(y0 + 1, IN_HW - 1);
        const int xm1 = max(a - 1, 0), xp1 = min(a + 1, IN_HW - 1);
        const int r0 = y0 * IN_HW, r1 = y1 * IN_HW;
        // 6 taps: rows y0,y1 x cols {a-1, a, a+1}, float4 of this lane's channels
        const float4 am = fT4[(r0 + xm1) * 16 + g];
        const float4 a0 = fT4[(r0 + a  ) * 16 + g];
        const float4 ap = fT4[(r0 + xp1) * 16 + g];
        const float4 bm = fT4[(r1 + xm1) * 16 + g];
        const float4 b0 = fT4[(r1 + a  ) * 16 + g];
        const float4 bp = fT4[(r1 + xp1) * 16 + g];

        const int ox = 4 * a + j;
        const int c = seg[oy * OUT_HW + ox];
        const float4 m4 = mn4[c * 16 + g];

        float fx = fminf(fmaxf(ox * 0.25f - 0.375f, 0.0f), (float)(IN_HW - 1));
        const int x0 = (int)fx; const float tx = fx - (float)x0;
        const bool lo = x0 < a;               // x0 == a-1 ?
        const float4 cL = lo ? am : a0;
        const float4 cR = lo ? a0 : ap;
        const float4 dL = lo ? bm : b0;
        const float4 dR = lo ? b0 : bp;

        float4 v;
        {
            float t0, t1;
            t0 = fmaf(tx, cR.x - cL.x, cL.x); t1 = fmaf(tx, dR.x - dL.x, dL.x);
            v.x = fmaf(ty, t1 - t0, t0);
            t0 = fmaf(tx, cR.y - cL.y, cL.y); t1 = fmaf(tx, dR.y - dL.y, dL.y);
            v.y = fmaf(ty, t1 - t0, t0);
            t0 = fmaf(tx, cR.z - cL.z, cL.z); t1 = fmaf(tx, dR.z - dL.z, dL.z);
            v.z = fmaf(ty, t1 - t0, t0);
            t0 = fmaf(tx, cR.w - cL.w, cL.w); t1 = fmaf(tx, dR.w - dL.w, dL.w);
            v.w = fmaf(ty, t1 - t0, t0);
        }
        float nr = fmaf(v.x, v.x, fmaf(v.y, v.y, fmaf(v.z, v.z, v.w * v.w)));
        float dt = fmaf(v.x, m4.x, fmaf(v.y, m4.y, fmaf(v.z, m4.z, v.w * m4.w)));
        // reduce across the 16 lanes of this pixel (4 pixels in parallel)
#pragma unroll
        for (int off = 1; off < 16; off <<= 1) {
            nr += __shfl_xor(nr, off);
            dt += __shfl_xor(dt, off);
        }
        const float w = 1.0f - dt / fmaxf(sqrtf(nr), EPSV); // mn==0 rows -> w==1 (mean path)

        float* __restrict__ arow = accL + c * STRIDE_ACC + 4 * g;
        atomicAdd(&arow[0], w * v.x);
        atomicAdd(&arow[1], w * v.y);
        atomicAdd(&arow[2], w * v.z);
        atomicAdd(&arow[3], w * v.w);
        if (g == 0) {
            atomicAdd(&accL[c * STRIDE_ACC + FEAT_CH], w);
            atomicAdd(&cntL[c], 1.0f);
        }
    }
    __syncthreads();

    // flush nonzeros via global atomics
    for (int i = tid; i < ACC_FLOATS; i += 256) {
        float v = accL[i];
        if (v != 0.0f) atomicAdd(&acc[i], v);
    }
    for (int i = tid; i < NUM_CLASSES; i += 256) {
        float v = cntL[i];
        if (v != 0.0f) atomicAdd(&acc[ACC_FLOATS + i], v);
    }
}

// ---- phase 2: momentum / is_zero / present selects ---------------------------
__global__ void k_final(const float* __restrict__ acc, const float* __restrict__ mem,
                        float* __restrict__ out) {
    const int c = blockIdx.x, k = threadIdx.x;   // 124 blocks x 64 threads (1 wave)
    const float a    = acc[c * STRIDE_ACC + k];
    const float wsum = acc[c * STRIDE_ACC + FEAT_CH];
    const float cnt  = acc[ACC_FLOATS + c];
    const float m = mem[c * FEAT_CH + k];
    const int is_zero = __all(m == 0.0f);
    const float divisor = (wsum > 0.0f) ? wsum : 1.0f;
    const float val = a / divisor;
    const float nw = is_zero ? val : fmaf(0.1f, val, 0.9f * m);
    out[c * FEAT_CH + k] = (cnt > 0.0f) ? nw : m;
}

extern "C" void kernel_launch(void* const* d_in, const int* in_sizes, int n_in,
                              void* d_out, int out_size, void* d_ws, size_t ws_size,
                              hipStream_t stream) {
    const float* feats  = (const float*)d_in[0];   // (1,64,120,120) f32
    const float* memory = (const float*)d_in[1];   // (124,1,64) f32
    const int*   seg    = (const int*)d_in[2];     // (1,480,480) i32
    float* out = (float*)d_out;                    // (124,1,64) f32
    float* ws  = (float*)d_ws;

    float* mn  = ws + WS_MN;
    float* acc = ws + WS_ACC;
    float* fT  = ws + WS_FT;

    const int tr_blocks = (NCELL * FEAT_CH) / 256;            // 3600
    k_prep<<<NUM_CLASSES + 32 + tr_blocks, 256, 0, stream>>>(memory, feats, mn, acc, fT);
    k_accum<<<NB_ACCUM, 256, 0, stream>>>(fT, seg, mn, acc);
    k_final<<<NUM_CLASSES, FEAT_CH, 0, stream>>>(acc, memory, out);
}

// Round 4
// 155.340 us; speedup vs baseline: 2.1327x; 1.0993x over previous
//
#include <hip/hip_runtime.h>
#include <math.h>

#define NUM_CLASSES 124
#define FEAT_CH     64
#define OUT_HW      480
#define IN_HW       120
#define NPIX        (OUT_HW * OUT_HW)
#define NCELL       (IN_HW * IN_HW)
#define NQUAD       (NPIX / 4)          // 57600: 120 quads/row x 480 rows
#define EPSV        1e-8f

// Accumulator layout: per class, 65 floats (64 ch + wsum), stride 65
#define STRIDE_ACC   65
#define ACC_FLOATS   (NUM_CLASSES * STRIDE_ACC)        // 8060
#define ACC_TOTAL    (ACC_FLOATS + NUM_CLASSES)        // 8184
#define NB_ACCUM     256                // 1 block/CU; 1024 thr = 16 waves

// ws layout (floats): mn[7936] | acc[8184] | fT[14400*64]
#define WS_MN   0
#define WS_ACC  (NUM_CLASSES * FEAT_CH)
#define WS_FT   (WS_ACC + ACC_TOTAL)

#define NTILE   (NCELL / 64)            // 225 transpose tiles

// ---- phase 0 (fused): normalize memory, zero acc, LDS-tiled transpose --------
__global__ __launch_bounds__(256) void k_prep(
        const float* __restrict__ mem, const float* __restrict__ feats,
        float* __restrict__ mn, float* __restrict__ acc, float* __restrict__ fT) {
    const int b = blockIdx.x;
    if (b < NUM_CLASSES) {
        if (threadIdx.x < FEAT_CH) {
            const int c = b, k = threadIdx.x;
            float v = mem[c * FEAT_CH + k];
            float s = v * v;
#pragma unroll
            for (int off = 32; off; off >>= 1) s += __shfl_xor(s, off);
            mn[c * FEAT_CH + k] = v / fmaxf(sqrtf(s), EPSV);
        }
    } else if (b < NUM_CLASSES + 32) {
        const int i = (b - NUM_CLASSES) * 256 + threadIdx.x;
        if (i < ACC_TOTAL) acc[i] = 0.0f;
    } else {
        // transpose tile: 64 cells x 64 channels through LDS (both sides coalesced)
        __shared__ float tileL[64 * 65];
        const int t = b - NUM_CLASSES - 32;        // 0..224
        const int q0 = t * 64;
        const int tid = threadIdx.x;
#pragma unroll
        for (int i = 0; i < 16; ++i) {
            const int idx = i * 256 + tid;         // 0..4095
            const int k = idx >> 6, q = idx & 63;  // lanes: q fast -> coalesced read
            tileL[q * 65 + k] = feats[k * NCELL + q0 + q];
        }
        __syncthreads();
#pragma unroll
        for (int i = 0; i < 16; ++i) {
            const int idx = i * 256 + tid;
            const int q = idx >> 6, k = idx & 63;  // lanes: k fast -> coalesced write
            fT[(q0 + q) * FEAT_CH + k] = tileL[q * 65 + k];
        }
    }
}

// ---- phase 1: wave = 4 output pixels (quad) x 16 lanes, 4 channels per lane --
__global__ __launch_bounds__(1024) void k_accum(
        const float* __restrict__ fT, const int* __restrict__ seg,
        const float* __restrict__ mn, float* __restrict__ acc) {
    __shared__ float accL[ACC_FLOATS];
    __shared__ float cntL[NUM_CLASSES];

    const int tid = threadIdx.x;
    for (int i = tid; i < ACC_FLOATS; i += 1024) accL[i] = 0.0f;
    for (int i = tid; i < NUM_CLASSES; i += 1024) cntL[i] = 0.0f;
    __syncthreads();

    const int lane = tid & 63;
    const int j = lane >> 4;          // pixel within quad (0..3)
    const int g = lane & 15;          // channel group (4 ch each)
    const int wid = (blockIdx.x * 1024 + tid) >> 6;
    const int nwaves = NB_ACCUM * 16; // 4096
    const float4* __restrict__ fT4 = (const float4*)fT;
    const float4* __restrict__ mn4 = (const float4*)mn;

    for (int Q = wid; Q < NQUAD; Q += nwaves) {
        const int oy = Q / 120;
        const int a  = Q - oy * 120;          // input column anchor
        float fy = fminf(fmaxf(oy * 0.25f - 0.375f, 0.0f), (float)(IN_HW - 1));
        const int y0 = (int)fy; const float ty = fy - (float)y0;
        const int y1 = min(y0 + 1, IN_HW - 1);
        const int xm1 = max(a - 1, 0), xp1 = min(a + 1, IN_HW - 1);
        const int r0 = y0 * IN_HW, r1 = y1 * IN_HW;
        // 6 taps: rows y0,y1 x cols {a-1, a, a+1}
        const float4 am = fT4[(r0 + xm1) * 16 + g];
        const float4 a0 = fT4[(r0 + a  ) * 16 + g];
        const float4 ap = fT4[(r0 + xp1) * 16 + g];
        const float4 bm = fT4[(r1 + xm1) * 16 + g];
        const float4 b0 = fT4[(r1 + a  ) * 16 + g];
        const float4 bp = fT4[(r1 + xp1) * 16 + g];

        const int ox = 4 * a + j;
        const int c = seg[oy * OUT_HW + ox];
        const float4 m4 = mn4[c * 16 + g];

        float fx = fminf(fmaxf(ox * 0.25f - 0.375f, 0.0f), (float)(IN_HW - 1));
        const int x0 = (int)fx; const float tx = fx - (float)x0;
        const bool lo = x0 < a;
        const float4 cL = lo ? am : a0;
        const float4 cR = lo ? a0 : ap;
        const float4 dL = lo ? bm : b0;
        const float4 dR = lo ? b0 : bp;

        float4 v;
        {
            float t0, t1;
            t0 = fmaf(tx, cR.x - cL.x, cL.x); t1 = fmaf(tx, dR.x - dL.x, dL.x);
            v.x = fmaf(ty, t1 - t0, t0);
            t0 = fmaf(tx, cR.y - cL.y, cL.y); t1 = fmaf(tx, dR.y - dL.y, dL.y);
            v.y = fmaf(ty, t1 - t0, t0);
            t0 = fmaf(tx, cR.z - cL.z, cL.z); t1 = fmaf(tx, dR.z - dL.z, dL.z);
            v.z = fmaf(ty, t1 - t0, t0);
            t0 = fmaf(tx, cR.w - cL.w, cL.w); t1 = fmaf(tx, dR.w - dL.w, dL.w);
            v.w = fmaf(ty, t1 - t0, t0);
        }
        float nr = fmaf(v.x, v.x, fmaf(v.y, v.y, fmaf(v.z, v.z, v.w * v.w)));
        float dt = fmaf(v.x, m4.x, fmaf(v.y, m4.y, fmaf(v.z, m4.z, v.w * m4.w)));
#pragma unroll
        for (int off = 1; off < 16; off <<= 1) {
            nr += __shfl_xor(nr, off);
            dt += __shfl_xor(dt, off);
        }
        const float w = 1.0f - dt / fmaxf(sqrtf(nr), EPSV); // mn==0 rows -> w==1

        float* __restrict__ arow = accL + c * STRIDE_ACC + 4 * g;
        atomicAdd(&arow[0], w * v.x);
        atomicAdd(&arow[1], w * v.y);
        atomicAdd(&arow[2], w * v.z);
        atomicAdd(&arow[3], w * v.w);
        if (g == 0) {
            atomicAdd(&accL[c * STRIDE_ACC + FEAT_CH], w);
            atomicAdd(&cntL[c], 1.0f);
        }
    }
    __syncthreads();

    // staggered flush: each block starts at a different rotation of the range
    const int off = (int)((blockIdx.x * 2017u) % ACC_FLOATS);
    for (int i0 = tid; i0 < ACC_FLOATS; i0 += 1024) {
        int i = i0 + off; if (i >= ACC_FLOATS) i -= ACC_FLOATS;
        float v = accL[i];
        if (v != 0.0f) atomicAdd(&acc[i], v);
    }
    for (int i0 = tid; i0 < NUM_CLASSES; i0 += 1024) {
        int i = i0 + (int)(blockIdx.x % NUM_CLASSES); if (i >= NUM_CLASSES) i -= NUM_CLASSES;
        float v = cntL[i];
        if (v != 0.0f) atomicAdd(&acc[ACC_FLOATS + i], v);
    }
}

// ---- phase 2: momentum / is_zero / present selects ---------------------------
__global__ void k_final(const float* __restrict__ acc, const float* __restrict__ mem,
                        float* __restrict__ out) {
    const int c = blockIdx.x, k = threadIdx.x;   // 124 blocks x 64 threads (1 wave)
    const float a    = acc[c * STRIDE_ACC + k];
    const float wsum = acc[c * STRIDE_ACC + FEAT_CH];
    const float cnt  = acc[ACC_FLOATS + c];
    const float m = mem[c * FEAT_CH + k];
    const int is_zero = __all(m == 0.0f);
    const float divisor = (wsum > 0.0f) ? wsum : 1.0f;
    const float val = a / divisor;
    const float nw = is_zero ? val : fmaf(0.1f, val, 0.9f * m);
    out[c * FEAT_CH + k] = (cnt > 0.0f) ? nw : m;
}

extern "C" void kernel_launch(void* const* d_in, const int* in_sizes, int n_in,
                              void* d_out, int out_size, void* d_ws, size_t ws_size,
                              hipStream_t stream) {
    const float* feats  = (const float*)d_in[0];   // (1,64,120,120) f32
    const float* memory = (const float*)d_in[1];   // (124,1,64) f32
    const int*   seg    = (const int*)d_in[2];     // (1,480,480) i32
    float* out = (float*)d_out;                    // (124,1,64) f32
    float* ws  = (float*)d_ws;

    float* mn  = ws + WS_MN;
    float* acc = ws + WS_ACC;
    float* fT  = ws + WS_FT;

    k_prep<<<NUM_CLASSES + 32 + NTILE, 256, 0, stream>>>(memory, feats, mn, acc, fT);
    k_accum<<<NB_ACCUM, 1024, 0, stream>>>(fT, seg, mn, acc);
    k_final<<<NUM_CLASSES, FEAT_CH, 0, stream>>>(acc, memory, out);
}

// Round 6
// 150.362 us; speedup vs baseline: 2.2033x; 1.0331x over previous
//
#include <hip/hip_runtime.h>
#include <math.h>

#define NUM_CLASSES 124
#define FEAT_CH     64
#define OUT_HW      480
#define IN_HW       120
#define NPIX        (OUT_HW * OUT_HW)
#define NCELL       (IN_HW * IN_HW)
#define NQUAD       (NPIX / 4)          // 57600 quads
#define EPSV        1e-8f

#define STRIDE_ACC   65
#define ACC_FLOATS   (NUM_CLASSES * STRIDE_ACC)        // 8060
#define ACC_TOTAL    (ACC_FLOATS + NUM_CLASSES)        // 8184
#define NB_ACCUM     256
#define NWAVES       (NB_ACCUM * 16)                   // 4096

// ws layout (floats): mn[7936] | acc[8184] | fT[14400*64]
#define WS_MN   0
#define WS_ACC  (NUM_CLASSES * FEAT_CH)
#define WS_FT   (WS_ACC + ACC_TOTAL)

#define NTILE   (NCELL / 64)            // 225 transpose tiles

// ---- phase 0 (fused): normalize memory, zero acc, LDS-tiled transpose --------
__global__ __launch_bounds__(256) void k_prep(
        const float* __restrict__ mem, const float* __restrict__ feats,
        float* __restrict__ mn, float* __restrict__ acc, float* __restrict__ fT) {
    const int b = blockIdx.x;
    if (b < NUM_CLASSES) {
        if (threadIdx.x < FEAT_CH) {
            const int c = b, k = threadIdx.x;
            float v = mem[c * FEAT_CH + k];
            float s = v * v;
#pragma unroll
            for (int off = 32; off; off >>= 1) s += __shfl_xor(s, off);
            mn[c * FEAT_CH + k] = v / fmaxf(sqrtf(s), EPSV);
        }
    } else if (b < NUM_CLASSES + 32) {
        const int i = (b - NUM_CLASSES) * 256 + threadIdx.x;
        if (i < ACC_TOTAL) acc[i] = 0.0f;
    } else {
        __shared__ float tileL[64 * 65];
        const int t = b - NUM_CLASSES - 32;        // 0..224
        const int q0 = t * 64;
        const int tid = threadIdx.x;
#pragma unroll
        for (int i = 0; i < 16; ++i) {
            const int idx = i * 256 + tid;
            const int k = idx >> 6, q = idx & 63;  // q fast -> coalesced read
            tileL[q * 65 + k] = feats[k * NCELL + q0 + q];
        }
        __syncthreads();
#pragma unroll
        for (int i = 0; i < 16; ++i) {
            const int idx = i * 256 + tid;
            const int q = idx >> 6, k = idx & 63;  // k fast -> coalesced write
            fT[(q0 + q) * FEAT_CH + k] = tileL[q * 65 + k];
        }
    }
}

// ---- DPP rotational butterfly: all-lanes sum within rows of 16 ---------------
template <int CTRL>
__device__ __forceinline__ float dpp_ror_add(float x) {
    int v = __builtin_amdgcn_update_dpp(0, __float_as_int(x), CTRL, 0xF, 0xF, false);
    return x + __int_as_float(v);
}
__device__ __forceinline__ void reduce16_pair(float& a, float& b) {
    a = dpp_ror_add<0x128>(a); b = dpp_ror_add<0x128>(b);   // row_ror:8
    a = dpp_ror_add<0x124>(a); b = dpp_ror_add<0x124>(b);   // row_ror:4
    a = dpp_ror_add<0x122>(a); b = dpp_ror_add<0x122>(b);   // row_ror:2
    a = dpp_ror_add<0x121>(a); b = dpp_ror_add<0x121>(b);   // row_ror:1
}

// ---- prefetch: issue all global loads for quad Q -----------------------------
__device__ __forceinline__ void issue_loads(int Q, int j, int g,
        const float4* __restrict__ fT4, const int* __restrict__ seg,
        const float4* __restrict__ mn4,
        float4& am, float4& a0, float4& ap,
        float4& bm, float4& b0, float4& bp, int& c, float4& m4) {
    const int oy = Q / 120;
    const int a  = Q - oy * 120;
    float fy = fminf(fmaxf(oy * 0.25f - 0.375f, 0.0f), (float)(IN_HW - 1));
    const int y0 = (int)fy;
    const int y1 = min(y0 + 1, IN_HW - 1);
    const int xm1 = max(a - 1, 0), xp1 = min(a + 1, IN_HW - 1);
    const int r0 = y0 * IN_HW, r1 = y1 * IN_HW;
    am = fT4[(r0 + xm1) * 16 + g];
    a0 = fT4[(r0 + a  ) * 16 + g];
    ap = fT4[(r0 + xp1) * 16 + g];
    bm = fT4[(r1 + xm1) * 16 + g];
    b0 = fT4[(r1 + a  ) * 16 + g];
    bp = fT4[(r1 + xp1) * 16 + g];
    c  = seg[oy * OUT_HW + 4 * a + j];
    m4 = mn4[c * 16 + g];
}

// ---- phase 1: wave = quad (4 px x 16 lanes), software-pipelined --------------
__global__ __launch_bounds__(1024, 4) void k_accum(
        const float* __restrict__ fT, const int* __restrict__ seg,
        const float* __restrict__ mn, float* __restrict__ acc) {
    __shared__ float accL[ACC_FLOATS];
    __shared__ float cntL[NUM_CLASSES];

    const int tid = threadIdx.x;
    for (int i = tid; i < ACC_FLOATS; i += 1024) accL[i] = 0.0f;
    for (int i = tid; i < NUM_CLASSES; i += 1024) cntL[i] = 0.0f;
    __syncthreads();

    const int lane = tid & 63;
    const int j = lane >> 4;          // pixel within quad
    const int g = lane & 15;          // channel group (4 ch)
    const int wid = (blockIdx.x * 1024 + tid) >> 6;
    const float4* __restrict__ fT4 = (const float4*)fT;
    const float4* __restrict__ mn4 = (const float4*)mn;

    // prefetch buffer
    float4 p_am, p_a0, p_ap, p_bm, p_b0, p_bp, p_m4; int p_c;
    issue_loads(min(wid, NQUAD - 1), j, g, fT4, seg, mn4,
                p_am, p_a0, p_ap, p_bm, p_b0, p_bp, p_c, p_m4);

    for (int Q = wid; Q < NQUAD; Q += NWAVES) {
        // consume prefetched
        const float4 am = p_am, a0 = p_a0, ap = p_ap;
        const float4 bm = p_bm, b0 = p_b0, bp = p_bp;
        const float4 m4 = p_m4; const int c = p_c;
        // issue next (wave-uniform branch)
        const int Qn = Q + NWAVES;
        if (Qn < NQUAD)
            issue_loads(Qn, j, g, fT4, seg, mn4,
                        p_am, p_a0, p_ap, p_bm, p_b0, p_bp, p_c, p_m4);

        // recompute scalars for Q (cheap)
        const int oy = Q / 120;
        const int a  = Q - oy * 120;
        float fy = fminf(fmaxf(oy * 0.25f - 0.375f, 0.0f), (float)(IN_HW - 1));
        const int y0 = (int)fy; const float ty = fy - (float)y0;
        const int ox = 4 * a + j;
        float fx = fminf(fmaxf(ox * 0.25f - 0.375f, 0.0f), (float)(IN_HW - 1));
        const int x0 = (int)fx; const float tx = fx - (float)x0;
        const bool lo = x0 < a;
        const float4 cL = lo ? am : a0;
        const float4 cR = lo ? a0 : ap;
        const float4 dL = lo ? bm : b0;
        const float4 dR = lo ? b0 : bp;

        float4 v;
        {
            float t0, t1;
            t0 = fmaf(tx, cR.x - cL.x, cL.x); t1 = fmaf(tx, dR.x - dL.x, dL.x);
            v.x = fmaf(ty, t1 - t0, t0);
            t0 = fmaf(tx, cR.y - cL.y, cL.y); t1 = fmaf(tx, dR.y - dL.y, dL.y);
            v.y = fmaf(ty, t1 - t0, t0);
            t0 = fmaf(tx, cR.z - cL.z, cL.z); t1 = fmaf(tx, dR.z - dL.z, dL.z);
            v.z = fmaf(ty, t1 - t0, t0);
            t0 = fmaf(tx, cR.w - cL.w, cL.w); t1 = fmaf(tx, dR.w - dL.w, dL.w);
            v.w = fmaf(ty, t1 - t0, t0);
        }
        float nr = fmaf(v.x, v.x, fmaf(v.y, v.y, fmaf(v.z, v.z, v.w * v.w)));
        float dt = fmaf(v.x, m4.x, fmaf(v.y, m4.y, fmaf(v.z, m4.z, v.w * m4.w)));
        reduce16_pair(nr, dt);                       // DPP, ~30 cyc
        const float w = 1.0f - dt / fmaxf(sqrtf(nr), EPSV); // mn==0 rows -> w==1

        float* __restrict__ arow = accL + c * STRIDE_ACC + 4 * g;
        atomicAdd(&arow[0], w * v.x);
        atomicAdd(&arow[1], w * v.y);
        atomicAdd(&arow[2], w * v.z);
        atomicAdd(&arow[3], w * v.w);
        if (g == 0) {
            atomicAdd(&accL[c * STRIDE_ACC + FEAT_CH], w);
            atomicAdd(&cntL[c], 1.0f);
        }
    }
    __syncthreads();

    // staggered flush
    const int off = (int)((blockIdx.x * 2017u) % ACC_FLOATS);
    for (int i0 = tid; i0 < ACC_FLOATS; i0 += 1024) {
        int i = i0 + off; if (i >= ACC_FLOATS) i -= ACC_FLOATS;
        float v = accL[i];
        if (v != 0.0f) atomicAdd(&acc[i], v);
    }
    for (int i0 = tid; i0 < NUM_CLASSES; i0 += 1024) {
        int i = i0 + (int)(blockIdx.x % NUM_CLASSES); if (i >= NUM_CLASSES) i -= NUM_CLASSES;
        float v = cntL[i];
        if (v != 0.0f) atomicAdd(&acc[ACC_FLOATS + i], v);
    }
}

// ---- phase 2: momentum / is_zero / present selects ---------------------------
__global__ void k_final(const float* __restrict__ acc, const float* __restrict__ mem,
                        float* __restrict__ out) {
    const int c = blockIdx.x, k = threadIdx.x;   // 124 blocks x 64 threads (1 wave)
    const float a    = acc[c * STRIDE_ACC + k];
    const float wsum = acc[c * STRIDE_ACC + FEAT_CH];
    const float cnt  = acc[ACC_FLOATS + c];
    const float m = mem[c * FEAT_CH + k];
    const int is_zero = __all(m == 0.0f);
    const float divisor = (wsum > 0.0f) ? wsum : 1.0f;
    const float val = a / divisor;
    const float nw = is_zero ? val : fmaf(0.1f, val, 0.9f * m);
    out[c * FEAT_CH + k] = (cnt > 0.0f) ? nw : m;
}

extern "C" void kernel_launch(void* const* d_in, const int* in_sizes, int n_in,
                              void* d_out, int out_size, void* d_ws, size_t ws_size,
                              hipStream_t stream) {
    const float* feats  = (const float*)d_in[0];   // (1,64,120,120) f32
    const float* memory = (const float*)d_in[1];   // (124,1,64) f32
    const int*   seg    = (const int*)d_in[2];     // (1,480,480) i32
    float* out = (float*)d_out;                    // (124,1,64) f32
    float* ws  = (float*)d_ws;

    float* mn  = ws + WS_MN;
    float* acc = ws + WS_ACC;
    float* fT  = ws + WS_FT;

    k_prep<<<NUM_CLASSES + 32 + NTILE, 256, 0, stream>>>(memory, feats, mn, acc, fT);
    k_accum<<<NB_ACCUM, 1024, 0, stream>>>(fT, seg, mn, acc);
    k_final<<<NUM_CLASSES, FEAT_CH, 0, stream>>>(acc, memory, out);
}